// Round 1
// baseline (37.958 us; speedup 1.0000x reference)
//
#include <hip/hip_runtime.h>

// Problem dims (fixed by reference):
//   sites     [4096, 128] f32
//   consensus [ 512, 128] f32
//   out = softmax(-L1dist, axis=-1)  -> [4096, 512] f32
#define N_SITES 4096
#define M_CONS  512
#define DIM     128

#define BROWS 128   // site rows per block
#define BCOLS 64    // consensus cols per block
#define KT    64    // k-tile (two passes over DIM)

// K1: negated L1 distance, tiled.
// Block: 256 threads = 4 waves arranged 2x2 (wave tile 64 rows x 32 cols).
// Thread: 8 rows (stride 8) x 4 cols (stride 8) accumulators.
// LDS: k-tile of sites (128x64) + consensus (64x64), f32, XOR-swizzled by
// float4-quad:  quad_stored = q ^ (row & 7)  -> conflict-free ds_read_b128
// for 8-consecutive-row access patterns, with natural 16B alignment.
__global__ __launch_bounds__(256) void dist_kernel(const float* __restrict__ sites,
                                                   const float* __restrict__ cons,
                                                   float* __restrict__ out) {
    __shared__ float s_sites[BROWS * KT];   // 32 KB
    __shared__ float s_cons[BCOLS * KT];    // 16 KB

    const int tid    = threadIdx.x;
    const int rowBlk = blockIdx.x;          // 0..31
    const int colBlk = blockIdx.y;          // 0..7

    const int wave = tid >> 6;              // 0..3
    const int lane = tid & 63;
    const int wr = wave >> 1;               // 0..1
    const int wc = wave & 1;                // 0..1
    const int lr = lane >> 3;               // 0..7 (row group)
    const int lc = lane & 7;                // 0..7 (col group)

    float acc[8][4];
#pragma unroll
    for (int i = 0; i < 8; i++)
#pragma unroll
        for (int j = 0; j < 4; j++) acc[i][j] = 0.f;

    for (int kt = 0; kt < DIM; kt += KT) {
        // ---- stage sites k-tile: 128 rows x 64 k = 2048 float4, 8 per thread
        {
            const float* gbase = sites + (size_t)rowBlk * BROWS * DIM + kt;
#pragma unroll
            for (int it = 0; it < 8; it++) {
                int f = tid + it * 256;         // 0..2047
                int r = f >> 4;                 // 16 quads per row
                int q = f & 15;
                float4 v = *(const float4*)(gbase + (size_t)r * DIM + (q << 2));
                int qs = q ^ (r & 7);
                *(float4*)&s_sites[r * KT + (qs << 2)] = v;
            }
        }
        // ---- stage consensus k-tile: 64 rows x 64 k = 1024 float4, 4 per thread
        {
            const float* gbase = cons + (size_t)colBlk * BCOLS * DIM + kt;
#pragma unroll
            for (int it = 0; it < 4; it++) {
                int f = tid + it * 256;         // 0..1023
                int r = f >> 4;
                int q = f & 15;
                float4 v = *(const float4*)(gbase + (size_t)r * DIM + (q << 2));
                int qs = q ^ (r & 7);
                *(float4*)&s_cons[r * KT + (qs << 2)] = v;
            }
        }
        __syncthreads();

        // ---- accumulate over this k-tile, 4 k at a time
#pragma unroll
        for (int q = 0; q < KT / 4; q++) {
            float4 sv[8], cv[4];
            const int qs_s = (q ^ lr) << 2;   // site rows have (row&7)==lr
            const int qs_c = (q ^ lc) << 2;   // cons rows have (row&7)==lc
#pragma unroll
            for (int i = 0; i < 8; i++) {
                int r = wr * 64 + 8 * i + lr;
                sv[i] = *(const float4*)&s_sites[r * KT + qs_s];
            }
#pragma unroll
            for (int j = 0; j < 4; j++) {
                int c = wc * 32 + 8 * j + lc;
                cv[j] = *(const float4*)&s_cons[c * KT + qs_c];
            }
#pragma unroll
            for (int i = 0; i < 8; i++) {
#pragma unroll
                for (int j = 0; j < 4; j++) {
                    acc[i][j] += fabsf(sv[i].x - cv[j].x);
                    acc[i][j] += fabsf(sv[i].y - cv[j].y);
                    acc[i][j] += fabsf(sv[i].z - cv[j].z);
                    acc[i][j] += fabsf(sv[i].w - cv[j].w);
                }
            }
        }
        __syncthreads();
    }

    // ---- write -dist (scalar stores; thread's cols are stride-8)
    const int grow0 = rowBlk * BROWS + wr * 64 + lr;
    const int gcol0 = colBlk * BCOLS + wc * 32 + lc;
#pragma unroll
    for (int i = 0; i < 8; i++) {
        float* orow = out + (size_t)(grow0 + 8 * i) * M_CONS + gcol0;
#pragma unroll
        for (int j = 0; j < 4; j++) {
            orow[8 * j] = -acc[i][j];
        }
    }
}

// K2: in-place row softmax over M_CONS=512. One wave per row, 8 f32/lane.
__global__ __launch_bounds__(256) void softmax_kernel(float* __restrict__ out) {
    const int row  = blockIdx.x * 4 + (threadIdx.x >> 6);
    const int lane = threadIdx.x & 63;
    float* p = out + (size_t)row * M_CONS + lane * 8;

    float4 v0 = *(const float4*)p;
    float4 v1 = *(const float4*)(p + 4);

    float m = fmaxf(fmaxf(fmaxf(v0.x, v0.y), fmaxf(v0.z, v0.w)),
                    fmaxf(fmaxf(v1.x, v1.y), fmaxf(v1.z, v1.w)));
#pragma unroll
    for (int off = 32; off > 0; off >>= 1) m = fmaxf(m, __shfl_xor(m, off));

    float e[8];
    e[0] = __expf(v0.x - m); e[1] = __expf(v0.y - m);
    e[2] = __expf(v0.z - m); e[3] = __expf(v0.w - m);
    e[4] = __expf(v1.x - m); e[5] = __expf(v1.y - m);
    e[6] = __expf(v1.z - m); e[7] = __expf(v1.w - m);

    float s = 0.f;
#pragma unroll
    for (int k = 0; k < 8; k++) s += e[k];
#pragma unroll
    for (int off = 32; off > 0; off >>= 1) s += __shfl_xor(s, off);

    const float inv = 1.f / s;
    float4 o0 = { e[0] * inv, e[1] * inv, e[2] * inv, e[3] * inv };
    float4 o1 = { e[4] * inv, e[5] * inv, e[6] * inv, e[7] * inv };
    *(float4*)p       = o0;
    *(float4*)(p + 4) = o1;
}

extern "C" void kernel_launch(void* const* d_in, const int* in_sizes, int n_in,
                              void* d_out, int out_size, void* d_ws, size_t ws_size,
                              hipStream_t stream) {
    const float* sites = (const float*)d_in[0];
    const float* cons  = (const float*)d_in[1];
    float* out = (float*)d_out;

    dim3 g1(N_SITES / BROWS, M_CONS / BCOLS);   // 32 x 8 = 256 blocks
    dist_kernel<<<g1, 256, 0, stream>>>(sites, cons, out);

    softmax_kernel<<<N_SITES / 4, 256, 0, stream>>>(out);
}

// Round 2
// 34.243 us; speedup vs baseline: 1.1085x; 1.1085x over previous
//
#include <hip/hip_runtime.h>

// sites [4096,128] f32, consensus [512,128] f32
// out = softmax(-L1dist, axis=-1) -> [4096,512] f32
#define N_SITES 4096
#define M_CONS  512
#define DIM     128

#define BROWS 128   // site rows per block
#define BCOLS 64    // consensus cols per block

// K1: negated L1 distance.
// Block: 512 threads = 8 waves = (kgroup 0..3) x (rowhalf 0..1).
// Wave: 64 rows x 64 cols x 32 k-dims (in-block split-k x4).
// Thread: 8x8 accumulators (lane = 8 lr x 8 lc).
// LDS 96KB: full-k tile of sites[128][128] + cons[64][128], f32, float4-quad
// XOR swizzle (stored quad = q ^ (row&7)) -> conflict-free broadcast
// ds_read_b128 for the 8-consecutive-row access pattern.
// After compute: k-groups 1..3 dump partials to LDS (reusing staging space),
// k-group 0 combines, negates, stores.
__global__ __launch_bounds__(512, 2) void dist_kernel(const float* __restrict__ sites,
                                                      const float* __restrict__ cons,
                                                      float* __restrict__ out) {
    __shared__ __align__(16) float lds[24576];      // 96 KB
    float* s_sites = lds;                           // [128][128] swizzled
    float* s_cons  = lds + BROWS * DIM;             // [64][128] swizzled

    const int tid    = threadIdx.x;
    const int rowBlk = blockIdx.x;                  // 0..31
    const int colBlk = blockIdx.y;                  // 0..7

    // ---- stage full tile: sites 4096 quads + cons 2048 quads, 12/thread
    {
        const float* gbase = sites + (size_t)rowBlk * BROWS * DIM;
#pragma unroll
        for (int it = 0; it < 8; it++) {
            int f = tid + it * 512;                 // 0..4095
            int r = f >> 5;                         // 32 quads per row
            int q = f & 31;
            float4 v = *(const float4*)(gbase + (size_t)r * DIM + (q << 2));
            int qs = q ^ (r & 7);
            *(float4*)&s_sites[r * DIM + (qs << 2)] = v;
        }
    }
    {
        const float* gbase = cons + (size_t)colBlk * BCOLS * DIM;
#pragma unroll
        for (int it = 0; it < 4; it++) {
            int f = tid + it * 512;                 // 0..2047
            int r = f >> 5;
            int q = f & 31;
            float4 v = *(const float4*)(gbase + (size_t)r * DIM + (q << 2));
            int qs = q ^ (r & 7);
            *(float4*)&s_cons[r * DIM + (qs << 2)] = v;
        }
    }

    const int wave = tid >> 6;
    const int lane = tid & 63;
    const int kg = wave >> 1;        // 0..3: k-dims [kg*32, kg*32+32)
    const int wr = wave & 1;         // row half: rows [wr*64, wr*64+64)
    const int lr = lane >> 3;        // 0..7
    const int lc = lane & 7;         // 0..7

    float acc[8][8];
#pragma unroll
    for (int i = 0; i < 8; i++)
#pragma unroll
        for (int j = 0; j < 8; j++) acc[i][j] = 0.f;

    __syncthreads();

    // ---- compute: 8 k-quads for this k-group
    const int q0 = kg << 3;
#pragma unroll 2
    for (int qq = 0; qq < 8; qq++) {
        const int q = q0 + qq;
        float4 sv[8], cv[8];
        const int qs_s = (q ^ lr) << 2;   // site rows of this thread have (r&7)==lr
        const int qs_c = (q ^ lc) << 2;   // cons rows of this thread have (c&7)==lc
#pragma unroll
        for (int i = 0; i < 8; i++) {
            int r = wr * 64 + 8 * i + lr;
            sv[i] = *(const float4*)&s_sites[r * DIM + qs_s];
        }
#pragma unroll
        for (int j = 0; j < 8; j++) {
            int c = 8 * j + lc;
            cv[j] = *(const float4*)&s_cons[c * DIM + qs_c];
        }
#pragma unroll
        for (int i = 0; i < 8; i++) {
#pragma unroll
            for (int j = 0; j < 8; j++) {
                acc[i][j] += fabsf(sv[i].x - cv[j].x);
                acc[i][j] += fabsf(sv[i].y - cv[j].y);
                acc[i][j] += fabsf(sv[i].z - cv[j].z);
                acc[i][j] += fabsf(sv[i].w - cv[j].w);
            }
        }
    }

    __syncthreads();   // compute done; staging space free for partials

    // ---- split-k combine through LDS. T = thread id within a k-group (0..127);
    // layout [slot 0..63][T]: consecutive lanes -> consecutive dwords, conflict-free.
    const int T = (wr << 6) | lane;
    if (kg > 0) {
        float* p = lds + (kg - 1) * 8192;
#pragma unroll
        for (int i = 0; i < 8; i++)
#pragma unroll
            for (int j = 0; j < 8; j++)
                p[(i * 8 + j) * 128 + T] = acc[i][j];
    }
    __syncthreads();
    if (kg == 0) {
        const int grow0 = rowBlk * BROWS + wr * 64 + lr;
        const int gcol0 = colBlk * BCOLS + lc;
#pragma unroll
        for (int i = 0; i < 8; i++) {
            float* orow = out + (size_t)(grow0 + 8 * i) * M_CONS + gcol0;
#pragma unroll
            for (int j = 0; j < 8; j++) {
                int s = (i * 8 + j) * 128 + T;
                float d = acc[i][j] + lds[s] + lds[8192 + s] + lds[16384 + s];
                orow[8 * j] = -d;
            }
        }
    }
}

// K2: in-place row softmax over M_CONS=512. One wave per row, 8 f32/lane.
__global__ __launch_bounds__(256) void softmax_kernel(float* __restrict__ out) {
    const int row  = blockIdx.x * 4 + (threadIdx.x >> 6);
    const int lane = threadIdx.x & 63;
    float* p = out + (size_t)row * M_CONS + lane * 8;

    float4 v0 = *(const float4*)p;
    float4 v1 = *(const float4*)(p + 4);

    float m = fmaxf(fmaxf(fmaxf(v0.x, v0.y), fmaxf(v0.z, v0.w)),
                    fmaxf(fmaxf(v1.x, v1.y), fmaxf(v1.z, v1.w)));
#pragma unroll
    for (int off = 32; off > 0; off >>= 1) m = fmaxf(m, __shfl_xor(m, off));

    float e[8];
    e[0] = __expf(v0.x - m); e[1] = __expf(v0.y - m);
    e[2] = __expf(v0.z - m); e[3] = __expf(v0.w - m);
    e[4] = __expf(v1.x - m); e[5] = __expf(v1.y - m);
    e[6] = __expf(v1.z - m); e[7] = __expf(v1.w - m);

    float s = 0.f;
#pragma unroll
    for (int k = 0; k < 8; k++) s += e[k];
#pragma unroll
    for (int off = 32; off > 0; off >>= 1) s += __shfl_xor(s, off);

    const float inv = 1.f / s;
    float4 o0 = { e[0] * inv, e[1] * inv, e[2] * inv, e[3] * inv };
    float4 o1 = { e[4] * inv, e[5] * inv, e[6] * inv, e[7] * inv };
    *(float4*)p       = o0;
    *(float4*)(p + 4) = o1;
}

extern "C" void kernel_launch(void* const* d_in, const int* in_sizes, int n_in,
                              void* d_out, int out_size, void* d_ws, size_t ws_size,
                              hipStream_t stream) {
    const float* sites = (const float*)d_in[0];
    const float* cons  = (const float*)d_in[1];
    float* out = (float*)d_out;

    dim3 g1(N_SITES / BROWS, M_CONS / BCOLS);   // 32 x 8 = 256 blocks, 1/CU
    dist_kernel<<<g1, 512, 0, stream>>>(sites, cons, out);

    softmax_kernel<<<N_SITES / 4, 256, 0, stream>>>(out);
}